// Round 1
// baseline (1069.473 us; speedup 1.0000x reference)
//
#include <hip/hip_runtime.h>

#define TT 8192
#define DD 512
#define NN 4
#define BM 64
#define BN 128
#define BK 32
#define JSPLIT 8
#define JRANGE (TT / JSPLIT)
#define LDA 68
#define LDB 132
#define LDC 132
#define BIGF 3.0e38f

// sorted ascending insert into 8-register top-list
__device__ __forceinline__ void ins8(float d, int j, float (&td)[8], int (&ti)[8]) {
  if (d < td[7]) {
    td[7] = d; ti[7] = j;
#pragma unroll
    for (int p = 7; p >= 1; --p) {
      float dl = td[p - 1], dh = td[p];
      int il = ti[p - 1], ih = ti[p];
      bool sw = dh < dl;
      td[p - 1] = sw ? dh : dl; ti[p - 1] = sw ? ih : il;
      td[p]     = sw ? dl : dh; ti[p]     = sw ? il : ih;
    }
  }
}

__global__ void sq_kernel(const float* __restrict__ X, float* __restrict__ sq) {
  int w = threadIdx.x >> 6, l = threadIdx.x & 63;
  int row = blockIdx.x * 4 + w;
  const float4* xr = (const float4*)(X + (size_t)row * DD) + l * 2;
  float4 a = xr[0], b = xr[1];
  float s = a.x * a.x + a.y * a.y + a.z * a.z + a.w * a.w +
            b.x * b.x + b.y * b.y + b.z * b.z + b.w * b.w;
#pragma unroll
  for (int off = 32; off >= 1; off >>= 1) s += __shfl_down(s, off, 64);
  if (l == 0) sq[row] = s;
}

// fused fp32 GEMM + per-row streaming top-8 per j-slice
__global__ __launch_bounds__(128) void gemm_topk(
    const float* __restrict__ X, const float* __restrict__ sq,
    float* __restrict__ cand_d2, int* __restrict__ cand_idx) {
  __shared__ float smem[8704];          // 34816 B: union{As(2176)+Bs(4224), Ct(8448), merge}
  float* As = smem;                     // [BK][LDA] transposed k-major
  float* Bs = smem + BK * LDA;
  float* Ct = smem;                     // [BM][LDC] overlay

  const int t = threadIdx.x;
  const int ty = t >> 4, tx = t & 15;
  const int bi = blockIdx.x & 127;      // 128 row-blocks
  const int bs = blockIdx.x >> 7;       // 8 j-slices
  const int i0 = bi * BM;
  const int j0b = bs * JRANGE;
  const float4* X4 = (const float4*)X;

  float sqi[8];
#pragma unroll
  for (int m = 0; m < 8; ++m)
    sqi[m] = sq[i0 + (m >> 2) * 32 + ty * 4 + (m & 3)];

  float td[8]; int ti[8];
#pragma unroll
  for (int s = 0; s < 8; ++s) { td[s] = BIGF; ti[s] = 0; }

  const int srow = t >> 1;              // scan row (2 threads/row)
  const int sh = (t & 1) * 64;          // column half

  for (int jt = 0; jt < JRANGE / BN; ++jt) {
    const int j0 = j0b + jt * BN;
    float ac[8][8];
#pragma unroll
    for (int m = 0; m < 8; ++m)
#pragma unroll
      for (int n = 0; n < 8; ++n) ac[m][n] = 0.f;

    for (int kt = 0; kt < DD / BK; ++kt) {
      __syncthreads();                  // protect LDS reuse (Ct overlay / prev reads)
#pragma unroll
      for (int q = 0; q < 4; ++q) {     // stage A: 64x32, transposed store
        int f = q * 128 + t;
        int row = f >> 3, c4 = f & 7;
        float4 v = X4[(size_t)(i0 + row) * (DD / 4) + kt * (BK / 4) + c4];
        As[(c4 * 4 + 0) * LDA + row] = v.x;
        As[(c4 * 4 + 1) * LDA + row] = v.y;
        As[(c4 * 4 + 2) * LDA + row] = v.z;
        As[(c4 * 4 + 3) * LDA + row] = v.w;
      }
#pragma unroll
      for (int q = 0; q < 8; ++q) {     // stage B: 128x32, transposed store
        int f = q * 128 + t;
        int row = f >> 3, c4 = f & 7;
        float4 v = X4[(size_t)(j0 + row) * (DD / 4) + kt * (BK / 4) + c4];
        Bs[(c4 * 4 + 0) * LDB + row] = v.x;
        Bs[(c4 * 4 + 1) * LDB + row] = v.y;
        Bs[(c4 * 4 + 2) * LDB + row] = v.z;
        Bs[(c4 * 4 + 3) * LDB + row] = v.w;
      }
      __syncthreads();
#pragma unroll 8
      for (int kk = 0; kk < BK; ++kk) {
        float4 a0 = *(const float4*)(As + kk * LDA + ty * 4);
        float4 a1 = *(const float4*)(As + kk * LDA + 32 + ty * 4);
        float4 b0 = *(const float4*)(Bs + kk * LDB + tx * 4);
        float4 b1 = *(const float4*)(Bs + kk * LDB + 64 + tx * 4);
        float av[8] = {a0.x, a0.y, a0.z, a0.w, a1.x, a1.y, a1.z, a1.w};
        float bv[8] = {b0.x, b0.y, b0.z, b0.w, b1.x, b1.y, b1.z, b1.w};
#pragma unroll
        for (int m = 0; m < 8; ++m)
#pragma unroll
          for (int n = 0; n < 8; ++n) ac[m][n] += av[m] * bv[n];
      }
    }
    __syncthreads();
    // epilogue: d2 = sq_i + sq_j - 2*dot into LDS tile
#pragma unroll
    for (int n = 0; n < 8; ++n) {
      int c = (n >> 2) * 64 + tx * 4 + (n & 3);
      float sj = sq[j0 + c];
#pragma unroll
      for (int m = 0; m < 8; ++m) {
        int r = (m >> 2) * 32 + ty * 4 + (m & 3);
        Ct[r * LDC + c] = sqi[m] + sj - 2.0f * ac[m][n];
      }
    }
    __syncthreads();
    // streaming selection: persistent per-(row,half) top-8
    for (int c = 0; c < 64; ++c) {
      float dv = Ct[srow * LDC + sh + c];
      ins8(dv, j0 + sh + c, td, ti);
    }
  }
  __syncthreads();
  // merge two half-lists per row -> slice top-8
#pragma unroll
  for (int s = 0; s < 8; ++s) {
    smem[srow * 16 + (t & 1) * 8 + s] = td[s];
    smem[2048 + srow * 16 + (t & 1) * 8 + s] = __int_as_float(ti[s]);
  }
  __syncthreads();
  if (t < 64) {
    float md[8]; int mi[8];
#pragma unroll
    for (int s = 0; s < 8; ++s) { md[s] = BIGF; mi[s] = 0; }
    for (int u = 0; u < 16; ++u) {
      float dv = smem[t * 16 + u];
      int jv = __float_as_int(smem[2048 + t * 16 + u]);
      ins8(dv, jv, md, mi);
    }
#pragma unroll
    for (int s = 0; s < 8; ++s) {
      cand_d2[(size_t)(i0 + t) * 64 + bs * 8 + s] = md[s];
      cand_idx[(size_t)(i0 + t) * 64 + bs * 8 + s] = mi[s];
    }
  }
}

// one wave per row: select top-8 of 64 candidates by approx d2, re-rank exactly in fp64
__global__ void refine_kernel(const float* __restrict__ X,
                              const float* __restrict__ cand_d2,
                              const int* __restrict__ cand_idx,
                              int* __restrict__ nb) {
  const int row = blockIdx.x;
  const int l = threadIdx.x;
  float dd = cand_d2[(size_t)row * 64 + l];
  int jj = cand_idx[(size_t)row * 64 + l];

  float xi[8];
  const float4* xr = (const float4*)(X + (size_t)row * DD) + l * 2;
  float4 xa = xr[0], xb = xr[1];
  xi[0] = xa.x; xi[1] = xa.y; xi[2] = xa.z; xi[3] = xa.w;
  xi[4] = xb.x; xi[5] = xb.y; xi[6] = xb.z; xi[7] = xb.w;

  int selj[8];
#pragma unroll
  for (int s = 0; s < 8; ++s) {
    float md = dd; int mj = jj;
#pragma unroll
    for (int off = 32; off >= 1; off >>= 1) {
      float od = __shfl_down(md, off, 64);
      int oj = __shfl_down(mj, off, 64);
      if (od < md || (od == md && oj < mj)) { md = od; mj = oj; }
    }
    mj = __shfl(mj, 0, 64);
    selj[s] = mj;
    if (jj == mj) dd = BIGF;   // candidate indices are unique
  }

  double ex[8];
#pragma unroll
  for (int s = 0; s < 8; ++s) {
    const float4* yr = (const float4*)(X + (size_t)selj[s] * DD) + l * 2;
    float4 ya = yr[0], yb = yr[1];
    float yv[8] = {ya.x, ya.y, ya.z, ya.w, yb.x, yb.y, yb.z, yb.w};
    double a = 0.0;
#pragma unroll
    for (int m = 0; m < 8; ++m) {
      double df = (double)xi[m] - (double)yv[m];
      a += df * df;
    }
#pragma unroll
    for (int off = 32; off >= 1; off >>= 1) a += __shfl_down(a, off, 64);
    ex[s] = __shfl(a, 0, 64);
  }

  if (l == 0) {
#pragma unroll
    for (int s = 0; s < 8; ++s) {
      int r = 0;
#pragma unroll
      for (int u = 0; u < 8; ++u)
        if (ex[u] < ex[s] || (ex[u] == ex[s] && selj[u] < selj[s])) ++r;
      if (r >= 1 && r <= 4) nb[(size_t)row * 4 + (r - 1)] = selj[s];  // rank0 = self
    }
  }
}

__global__ void gen_kernel(const float* __restrict__ X,
                           const float* __restrict__ gaps,
                           const int* __restrict__ nnc,
                           const int* __restrict__ nb,
                           float* __restrict__ out) {
  int o = blockIdx.x * 2 + (threadIdx.x >> 7);
  int t = threadIdx.x & 127;
  int i = o >> 2;
  float g = gaps[o];
  int c = nnc[o];
  int s = nb[i * 4 + c];
  const float4* X4 = (const float4*)X;
  float4 b = X4[(size_t)i * 128 + t];
  float4 sv = X4[(size_t)s * 128 + t];
  float4 r;
  r.x = b.x + g * (sv.x - b.x);
  r.y = b.y + g * (sv.y - b.y);
  r.z = b.z + g * (sv.z - b.z);
  r.w = b.w + g * (sv.w - b.w);
  ((float4*)out)[(size_t)o * 128 + t] = r;
}

extern "C" void kernel_launch(void* const* d_in, const int* in_sizes, int n_in,
                              void* d_out, int out_size, void* d_ws, size_t ws_size,
                              hipStream_t stream) {
  const float* X = (const float*)d_in[0];
  const float* gaps = (const float*)d_in[1];
  const int* nnc = (const int*)d_in[2];
  float* out = (float*)d_out;

  // workspace layout (4.16 MB total)
  float* sq = (float*)d_ws;
  float* cand_d2 = (float*)((char*)d_ws + 32768);
  int* cand_idx = (int*)((char*)d_ws + 32768 + 2097152);
  int* nb = (int*)((char*)d_ws + 32768 + 2 * 2097152);

  sq_kernel<<<TT / 4, 256, 0, stream>>>(X, sq);
  gemm_topk<<<(TT / BM) * JSPLIT, 128, 0, stream>>>(X, sq, cand_d2, cand_idx);
  refine_kernel<<<TT, 64, 0, stream>>>(X, cand_d2, cand_idx, nb);
  gen_kernel<<<TT * NN / 2, 256, 0, stream>>>(X, gaps, nnc, nb, out);
}

// Round 2
// 293.423 us; speedup vs baseline: 3.6448x; 3.6448x over previous
//
#include <hip/hip_runtime.h>

#define TT 8192
#define DD 512
#define NN 4
#define JS 16
#define JR (TT / JS)        // 512 columns per slice
#define BIGU 0xFFFFFFFFu
#define BIGF 3.0e38f

typedef unsigned int uint;
typedef unsigned short ushort;
typedef __attribute__((ext_vector_type(8))) short short8;   // 8 bf16 = 4 VGPRs
typedef __attribute__((ext_vector_type(4))) float f32x4;

// ---- fp32 -> bf16 (RTN-even) ----
__device__ __forceinline__ uint bfr(float f) {
  uint u = __float_as_uint(f);
  return (u + 0x7FFFu + ((u >> 16) & 1u)) >> 16;
}

__global__ void cvt_kernel(const float* __restrict__ X, uint4* __restrict__ Xb) {
  int t = blockIdx.x * 256 + threadIdx.x;            // 524288 threads, 8 floats each
  const float4* s = (const float4*)X + (size_t)t * 2;
  float4 a = s[0], b = s[1];
  uint4 o;
  o.x = bfr(a.x) | (bfr(a.y) << 16);
  o.y = bfr(a.z) | (bfr(a.w) << 16);
  o.z = bfr(b.x) | (bfr(b.y) << 16);
  o.w = bfr(b.z) | (bfr(b.w) << 16);
  Xb[t] = o;
}

__global__ void sq_kernel(const float* __restrict__ X, float* __restrict__ sq) {
  int w = threadIdx.x >> 6, l = threadIdx.x & 63;
  int row = blockIdx.x * 4 + w;
  const float4* xr = (const float4*)(X + (size_t)row * DD) + l * 2;
  float4 a = xr[0], b = xr[1];
  float s = a.x * a.x + a.y * a.y + a.z * a.z + a.w * a.w +
            b.x * b.x + b.y * b.y + b.z * b.z + b.w * b.w;
#pragma unroll
  for (int off = 32; off >= 1; off >>= 1) s += __shfl_down(s, off, 64);
  if (l == 0) sq[row] = s;
}

// global->LDS async 16B; integer-cast route for address spaces (flat low-32 == LDS offset)
__device__ __forceinline__ void gload16(const void* g, void* l) {
  __builtin_amdgcn_global_load_lds(
      (const __attribute__((address_space(1))) void*)(size_t)g,
      (__attribute__((address_space(3))) void*)(uint)(size_t)l, 16, 0, 0);
}

// bf16-MFMA distance GEMM (transposed: m=j, n=i) + in-register per-row top-4/lane
__global__ __launch_bounds__(256, 3) void gemm_topk(
    const ushort* __restrict__ Xb, const float* __restrict__ sqv,
    uint* __restrict__ ckey) {
  __shared__ uint4 smemv[1056];       // 16896 B: GEMM {As 8K + Bs 8K} / merge [128][33] uint
  char* AsB = (char*)smemv;           // i-rows [128][32] bf16, row-major, unpadded
  char* BsB = AsB + 8192;             // j-rows [128][32] bf16

  const int t = threadIdx.x;
  const int w = t >> 6, l = t & 63;
  const int l15 = l & 15, q4 = l >> 4;
  const int bi = blockIdx.x >> 4;     // 64 row-blocks
  const int bs = blockIdx.x & 15;     // 16 j-slices
  const int i0 = bi * 128;
  const int js0 = bs * JR;
  const char* XbB = (const char*)Xb;

  const int srow = l >> 2, schunk = l & 3;   // staging: lane -> (row, 16B chunk)
  const int mq = (w & 1) * 64;        // wave's j-quadrant
  const int nq = (w >> 1) * 64;       // wave's i-quadrant

  uint L[4][4];                       // per-(lane, i-row frag) top-4 packed keys
#pragma unroll
  for (int cb = 0; cb < 4; ++cb)
#pragma unroll
    for (int s = 0; s < 4; ++s) L[cb][s] = BIGU;

  for (int jt = 0; jt < JR / 128; ++jt) {
    const int jb = js0 + jt * 128;
    f32x4 acc[4][4];
#pragma unroll
    for (int rb = 0; rb < 4; ++rb)
#pragma unroll
      for (int cb = 0; cb < 4; ++cb) {
        f32x4 z = {0.f, 0.f, 0.f, 0.f};
        acc[rb][cb] = z;
      }

    for (int kt = 0; kt < DD / 32; ++kt) {
      __syncthreads();                 // readers of previous k-tile done
#pragma unroll
      for (int q = 0; q < 2; ++q) {    // each wave stages 32 i-rows + 32 j-rows
        int r = w * 32 + q * 16;
        gload16(XbB + (size_t)(i0 + r + srow) * 1024 + kt * 64 + schunk * 16,
                AsB + r * 64);
        gload16(XbB + (size_t)(jb + r + srow) * 1024 + kt * 64 + schunk * 16,
                BsB + r * 64);
      }
      __syncthreads();                 // vmcnt(0) drained by barrier semantics
      short8 af[4], bf[4];
#pragma unroll
      for (int rb = 0; rb < 4; ++rb)   // A-operand = j-rows (from Bs)
        af[rb] = *(const short8*)(BsB + (mq + rb * 16 + l15) * 64 + q4 * 16);
#pragma unroll
      for (int cb = 0; cb < 4; ++cb)   // B-operand = i-rows (from As)
        bf[cb] = *(const short8*)(AsB + (nq + cb * 16 + l15) * 64 + q4 * 16);
#pragma unroll
      for (int rb = 0; rb < 4; ++rb)
#pragma unroll
        for (int cb = 0; cb < 4; ++cb)
          acc[rb][cb] = __builtin_amdgcn_mfma_f32_16x16x32_bf16(
              af[rb], bf[cb], acc[rb][cb], 0, 0, 0);
    }

    // selection: key = sq[j] - 2*dot (sq[i] constant per row -> order-equivalent)
    // D layout: col(lane&15)=i-local, row(q4*4+reg)=j-local
#pragma unroll
    for (int rb = 0; rb < 4; ++rb) {
      int jg = jb + mq + rb * 16 + q4 * 4;
      float4 sj = *(const float4*)(sqv + jg);
      float s4[4] = {sj.x, sj.y, sj.z, sj.w};
#pragma unroll
      for (int cb = 0; cb < 4; ++cb) {
#pragma unroll
        for (int r = 0; r < 4; ++r) {
          float key = fmaf(-2.f, acc[rb][cb][r], s4[r]);
          uint u = __float_as_uint(key);
          u ^= (uint)((int)u >> 31) | 0x80000000u;       // orderable uint
          uint p = (u & 0xFFFFE000u) | (uint)(jg + r);   // 19b key | 13b j
          if (p < L[cb][3]) {
            L[cb][3] = p;
#pragma unroll
            for (int s = 3; s >= 1; --s) {
              uint lo = L[cb][s - 1], hi = L[cb][s];
              bool sw = hi < lo;
              L[cb][s - 1] = sw ? hi : lo;
              L[cb][s] = sw ? lo : hi;
            }
          }
        }
      }
    }
  }

  __syncthreads();                     // done with As/Bs; overlay merge buffer
  uint* ml = (uint*)smemv;             // [128 rows][33] (pad -> bank shift)
  const int cid = (w & 1) * 4 + q4;    // 8 contributors per row
#pragma unroll
  for (int cb = 0; cb < 4; ++cb) {
    int n = nq + cb * 16 + l15;
#pragma unroll
    for (int s = 0; s < 4; ++s) ml[n * 33 + cid * 4 + s] = L[cb][s];
  }
  __syncthreads();
  if (t < 128) {
    uint best[8];
#pragma unroll
    for (int s = 0; s < 8; ++s) best[s] = BIGU;
    for (int u = 0; u < 32; ++u) {
      uint p = ml[t * 33 + u];
      if (p < best[7]) {
        best[7] = p;
#pragma unroll
        for (int s = 7; s >= 1; --s) {
          uint lo = best[s - 1], hi = best[s];
          bool sw = hi < lo;
          best[s - 1] = sw ? hi : lo;
          best[s] = sw ? lo : hi;
        }
      }
    }
#pragma unroll
    for (int s = 0; s < 8; ++s)
      ckey[(size_t)(i0 + t) * 128 + bs * 8 + s] = best[s];
  }
}

// one wave per row: approx-top-8 of 128 packed candidates, exact fp64 re-rank
__global__ void refine_kernel(const float* __restrict__ X,
                              const uint* __restrict__ ckey,
                              int* __restrict__ nb) {
  const int row = blockIdx.x;
  const int l = threadIdx.x;
  uint k0 = ckey[(size_t)row * 128 + l];
  uint k1 = ckey[(size_t)row * 128 + 64 + l];

  float xi[8];
  const float4* xr = (const float4*)(X + (size_t)row * DD) + l * 2;
  float4 xa = xr[0], xb = xr[1];
  xi[0] = xa.x; xi[1] = xa.y; xi[2] = xa.z; xi[3] = xa.w;
  xi[4] = xb.x; xi[5] = xb.y; xi[6] = xb.z; xi[7] = xb.w;

  int selj[8];
#pragma unroll
  for (int s = 0; s < 8; ++s) {
    uint m = k0 < k1 ? k0 : k1;
#pragma unroll
    for (int off = 32; off >= 1; off >>= 1) {
      uint o = __shfl_down(m, off, 64);
      m = o < m ? o : m;
    }
    m = __shfl(m, 0, 64);
    selj[s] = (int)(m & 8191u);        // j embedded; packed values unique
    if (k0 == m) k0 = BIGU;
    if (k1 == m) k1 = BIGU;
  }

  double ex[8];
#pragma unroll
  for (int s = 0; s < 8; ++s) {
    const float4* yr = (const float4*)(X + (size_t)selj[s] * DD) + l * 2;
    float4 ya = yr[0], yb = yr[1];
    float yv[8] = {ya.x, ya.y, ya.z, ya.w, yb.x, yb.y, yb.z, yb.w};
    double a = 0.0;
#pragma unroll
    for (int m = 0; m < 8; ++m) {
      double df = (double)xi[m] - (double)yv[m];
      a += df * df;
    }
#pragma unroll
    for (int off = 32; off >= 1; off >>= 1) a += __shfl_down(a, off, 64);
    ex[s] = __shfl(a, 0, 64);
  }

  if (l == 0) {
#pragma unroll
    for (int s = 0; s < 8; ++s) {
      int r = 0;
#pragma unroll
      for (int u = 0; u < 8; ++u)
        if (ex[u] < ex[s] || (ex[u] == ex[s] && selj[u] < selj[s])) ++r;
      if (r >= 1 && r <= 4) nb[(size_t)row * 4 + (r - 1)] = selj[s];  // rank0 = self
    }
  }
}

__global__ void gen_kernel(const float* __restrict__ X,
                           const float* __restrict__ gaps,
                           const int* __restrict__ nnc,
                           const int* __restrict__ nb,
                           float* __restrict__ out) {
  int o = blockIdx.x * 2 + (threadIdx.x >> 7);
  int t = threadIdx.x & 127;
  int i = o >> 2;
  float g = gaps[o];
  int c = nnc[o];
  int s = nb[i * 4 + c];
  const float4* X4 = (const float4*)X;
  float4 b = X4[(size_t)i * 128 + t];
  float4 sv = X4[(size_t)s * 128 + t];
  float4 r;
  r.x = b.x + g * (sv.x - b.x);
  r.y = b.y + g * (sv.y - b.y);
  r.z = b.z + g * (sv.z - b.z);
  r.w = b.w + g * (sv.w - b.w);
  ((float4*)out)[(size_t)o * 128 + t] = r;
}

extern "C" void kernel_launch(void* const* d_in, const int* in_sizes, int n_in,
                              void* d_out, int out_size, void* d_ws, size_t ws_size,
                              hipStream_t stream) {
  const float* X = (const float*)d_in[0];
  const float* gaps = (const float*)d_in[1];
  const int* nnc = (const int*)d_in[2];
  float* out = (float*)d_out;

  // workspace layout (~12.7 MB)
  float* sqv = (float*)d_ws;                                        // 32 KB
  uint4* Xb4 = (uint4*)((char*)d_ws + 32768);                       // 8 MB bf16 X
  uint* ckey = (uint*)((char*)d_ws + 32768 + 8388608);              // 4 MB candidates
  int* nb = (int*)((char*)d_ws + 32768 + 8388608 + 4194304);        // 128 KB

  cvt_kernel<<<2048, 256, 0, stream>>>(X, Xb4);
  sq_kernel<<<TT / 4, 256, 0, stream>>>(X, sqv);
  gemm_topk<<<1024, 256, 0, stream>>>((const ushort*)Xb4, sqv, ckey);
  refine_kernel<<<TT, 64, 0, stream>>>(X, ckey, nb);
  gen_kernel<<<TT * NN / 2, 256, 0, stream>>>(X, gaps, nnc, nb, out);
}

// Round 3
// 257.371 us; speedup vs baseline: 4.1554x; 1.1401x over previous
//
#include <hip/hip_runtime.h>

#define TT 8192
#define DD 512
#define NN 4
#define JS 16
#define JR (TT / JS)        // 512 columns per slice
#define BIGU 0xFFFFFFFFu

typedef unsigned int uint;
typedef unsigned short ushort;
typedef __attribute__((ext_vector_type(8))) short short8;   // 8 bf16 = 4 VGPRs
typedef __attribute__((ext_vector_type(4))) float f32x4;

// ---- fp32 -> bf16 (RTN-even) ----
__device__ __forceinline__ uint bfr(float f) {
  uint u = __float_as_uint(f);
  return (u + 0x7FFFu + ((u >> 16) & 1u)) >> 16;
}

// fused: bf16 convert + row sum-of-squares
__global__ void cvtsq_kernel(const float* __restrict__ X, uint4* __restrict__ Xb,
                             float* __restrict__ sq) {
  int w = threadIdx.x >> 6, l = threadIdx.x & 63;
  int row = blockIdx.x * 4 + w;
  const float4* xr = (const float4*)(X + (size_t)row * DD) + l * 2;
  float4 a = xr[0], b = xr[1];
  uint4 o;
  o.x = bfr(a.x) | (bfr(a.y) << 16);
  o.y = bfr(a.z) | (bfr(a.w) << 16);
  o.z = bfr(b.x) | (bfr(b.y) << 16);
  o.w = bfr(b.z) | (bfr(b.w) << 16);
  Xb[(size_t)row * 64 + l] = o;
  float s = a.x * a.x + a.y * a.y + a.z * a.z + a.w * a.w +
            b.x * b.x + b.y * b.y + b.z * b.z + b.w * b.w;
#pragma unroll
  for (int off = 32; off >= 1; off >>= 1) s += __shfl_down(s, off, 64);
  if (l == 0) sq[row] = s;
}

// global->LDS async 16B
__device__ __forceinline__ void gload16(const void* g, void* l) {
  __builtin_amdgcn_global_load_lds(
      (const __attribute__((address_space(1))) void*)(size_t)g,
      (__attribute__((address_space(3))) void*)(uint)(size_t)l, 16, 0, 0);
}

// bf16-MFMA distance GEMM (transposed: m=j, n=i), BK=64, XOR-swizzled LDS,
// in-register per-row top-4/lane streaming selection
__global__ __launch_bounds__(256, 3) void gemm_topk(
    const ushort* __restrict__ Xb, const float* __restrict__ sqv,
    uint* __restrict__ ckey) {
  __shared__ char smem[32768];        // As 16K + Bs 16K; merge overlays As
  char* AsB = smem;                   // i-rows [128][8 x 16B chunks, pos = c^(r&7)]
  char* BsB = smem + 16384;           // j-rows, same layout

  const int t = threadIdx.x;
  const int w = t >> 6, l = t & 63;
  const int l15 = l & 15, q4 = l >> 4;
  const int bi = blockIdx.x >> 4;     // 64 row-blocks
  const int bs = blockIdx.x & 15;     // 16 j-slices
  const int i0 = bi * 128;
  const int js0 = bs * JR;
  const char* XbB = (const char*)Xb;

  const int srow8 = l >> 3;           // staging: lane -> row-in-8, chunk-pos
  const int scp = l & 7;
  const int mq = (w & 1) * 64;        // wave's j-quadrant
  const int nq = (w >> 1) * 64;       // wave's i-quadrant

  uint L[4][4];                       // per-(lane, i-frag) top-4 packed keys
#pragma unroll
  for (int cb = 0; cb < 4; ++cb)
#pragma unroll
    for (int s = 0; s < 4; ++s) L[cb][s] = BIGU;

  for (int jt = 0; jt < JR / 128; ++jt) {
    const int jb = js0 + jt * 128;
    f32x4 acc[4][4];
#pragma unroll
    for (int rb = 0; rb < 4; ++rb)
#pragma unroll
      for (int cb = 0; cb < 4; ++cb) {
        f32x4 z = {0.f, 0.f, 0.f, 0.f};
        acc[rb][cb] = z;
      }

    for (int kt = 0; kt < DD / 64; ++kt) {     // 8 stages per j-tile
      __syncthreads();                 // readers of previous k-tile done
#pragma unroll
      for (int q = 0; q < 4; ++q) {    // each wave: 32 A-rows + 32 B-rows
        int r = w * 32 + q * 8 + srow8;
        int c = scp ^ (r & 7);         // swizzled source chunk
        gload16(XbB + (size_t)(i0 + r) * 1024 + kt * 128 + c * 16,
                AsB + (w * 32 + q * 8) * 128);
        gload16(XbB + (size_t)(jb + r) * 1024 + kt * 128 + c * 16,
                BsB + (w * 32 + q * 8) * 128);
      }
      __syncthreads();
#pragma unroll
      for (int kk = 0; kk < 2; ++kk) { // two 16x16x32 k-steps per stage
        const int cc = kk * 4 + q4;
        short8 af[4], bf[4];
#pragma unroll
        for (int rb = 0; rb < 4; ++rb) {   // A-operand = j-rows (from Bs)
          int rr = mq + rb * 16 + l15;
          af[rb] = *(const short8*)(BsB + rr * 128 + ((cc ^ (rr & 7)) * 16));
        }
#pragma unroll
        for (int cb = 0; cb < 4; ++cb) {   // B-operand = i-rows (from As)
          int rr = nq + cb * 16 + l15;
          bf[cb] = *(const short8*)(AsB + rr * 128 + ((cc ^ (rr & 7)) * 16));
        }
#pragma unroll
        for (int rb = 0; rb < 4; ++rb)
#pragma unroll
          for (int cb = 0; cb < 4; ++cb)
            acc[rb][cb] = __builtin_amdgcn_mfma_f32_16x16x32_bf16(
                af[rb], bf[cb], acc[rb][cb], 0, 0, 0);
      }
    }

    // selection: key = sq[j] - 2*dot (sq[i] const per row -> order-equivalent)
    // D layout: col(lane&15)=i-local, row(q4*4+reg)=j-local
#pragma unroll
    for (int rb = 0; rb < 4; ++rb) {
      int jg = jb + mq + rb * 16 + q4 * 4;
      float4 sj = *(const float4*)(sqv + jg);
      float s4[4] = {sj.x, sj.y, sj.z, sj.w};
#pragma unroll
      for (int cb = 0; cb < 4; ++cb) {
#pragma unroll
        for (int r = 0; r < 4; ++r) {
          float key = fmaf(-2.f, acc[rb][cb][r], s4[r]);
          uint u = __float_as_uint(key);
          u ^= (uint)((int)u >> 31) | 0x80000000u;       // orderable uint
          uint p = (u & 0xFFFFE000u) | (uint)(jg + r);   // 19b key | 13b j
          if (p < L[cb][3]) {
            L[cb][3] = p;
#pragma unroll
            for (int s = 3; s >= 1; --s) {
              uint lo = L[cb][s - 1], hi = L[cb][s];
              bool sw = hi < lo;
              L[cb][s - 1] = sw ? hi : lo;
              L[cb][s] = sw ? lo : hi;
            }
          }
        }
      }
    }
  }

  __syncthreads();                     // done with As/Bs; overlay merge buffer
  uint* ml = (uint*)smem;              // [128 rows][33]
  const int cid = (w & 1) * 4 + q4;    // 8 contributors per row
#pragma unroll
  for (int cb = 0; cb < 4; ++cb) {
    int n = nq + cb * 16 + l15;
#pragma unroll
    for (int s = 0; s < 4; ++s) ml[n * 33 + cid * 4 + s] = L[cb][s];
  }
  __syncthreads();
  if (t < 128) {
    uint best[8];
#pragma unroll
    for (int s = 0; s < 8; ++s) best[s] = BIGU;
    for (int u = 0; u < 32; ++u) {
      uint p = ml[t * 33 + u];
      if (p < best[7]) {
        best[7] = p;
#pragma unroll
        for (int s = 7; s >= 1; --s) {
          uint lo = best[s - 1], hi = best[s];
          bool sw = hi < lo;
          best[s - 1] = sw ? hi : lo;
          best[s] = sw ? lo : hi;
        }
      }
    }
#pragma unroll
    for (int s = 0; s < 8; ++s)
      ckey[(size_t)(i0 + t) * 128 + bs * 8 + s] = best[s];
  }
}

// fused: approx-top-8 of 128 candidates, exact fp64 re-rank, interpolate + write
__global__ void refine_gen(const float* __restrict__ X,
                           const uint* __restrict__ ckey,
                           const float* __restrict__ gaps,
                           const int* __restrict__ nnc,
                           float* __restrict__ out) {
  const int row = blockIdx.x;
  const int l = threadIdx.x;
  uint k0 = ckey[(size_t)row * 128 + l];
  uint k1 = ckey[(size_t)row * 128 + 64 + l];

  float xi[8];
  const float4* xr = (const float4*)(X + (size_t)row * DD) + l * 2;
  float4 xa = xr[0], xb = xr[1];
  xi[0] = xa.x; xi[1] = xa.y; xi[2] = xa.z; xi[3] = xa.w;
  xi[4] = xb.x; xi[5] = xb.y; xi[6] = xb.z; xi[7] = xb.w;

  int selj[8];
#pragma unroll
  for (int s = 0; s < 8; ++s) {
    uint m = k0 < k1 ? k0 : k1;
#pragma unroll
    for (int off = 32; off >= 1; off >>= 1) {
      uint o = __shfl_down(m, off, 64);
      m = o < m ? o : m;
    }
    m = __shfl(m, 0, 64);
    selj[s] = (int)(m & 8191u);        // j embedded; packed values unique
    if (k0 == m) k0 = BIGU;
    if (k1 == m) k1 = BIGU;
  }

  float yv[8][8];
  double ex[8];
#pragma unroll
  for (int s = 0; s < 8; ++s) {
    const float4* yr = (const float4*)(X + (size_t)selj[s] * DD) + l * 2;
    float4 ya = yr[0], yb = yr[1];
    yv[s][0] = ya.x; yv[s][1] = ya.y; yv[s][2] = ya.z; yv[s][3] = ya.w;
    yv[s][4] = yb.x; yv[s][5] = yb.y; yv[s][6] = yb.z; yv[s][7] = yb.w;
    double a = 0.0;
#pragma unroll
    for (int m = 0; m < 8; ++m) {
      double df = (double)xi[m] - (double)yv[s][m];
      a += df * df;
    }
#pragma unroll
    for (int off = 32; off >= 1; off >>= 1) a += __shfl_down(a, off, 64);
    ex[s] = __shfl(a, 0, 64);          // broadcast to all lanes
  }

  int rk[8];                           // exact ranks (rank 0 = self)
#pragma unroll
  for (int s = 0; s < 8; ++s) {
    int r = 0;
#pragma unroll
    for (int u = 0; u < 8; ++u)
      if (ex[u] < ex[s] || (ex[u] == ex[s] && selj[u] < selj[s])) ++r;
    rk[s] = r;
  }

#pragma unroll
  for (int o = 0; o < 4; ++o) {
    float g = gaps[row * 4 + o];
    int target = nnc[row * 4 + o] + 1; // skip self (rank 0)
    float ys[8];
#pragma unroll
    for (int m = 0; m < 8; ++m) ys[m] = 0.f;
#pragma unroll
    for (int s = 0; s < 8; ++s) {
      bool hit = (rk[s] == target);
#pragma unroll
      for (int m = 0; m < 8; ++m) ys[m] = hit ? yv[s][m] : ys[m];
    }
    float4 r0, r1;
    r0.x = fmaf(g, ys[0] - xi[0], xi[0]);
    r0.y = fmaf(g, ys[1] - xi[1], xi[1]);
    r0.z = fmaf(g, ys[2] - xi[2], xi[2]);
    r0.w = fmaf(g, ys[3] - xi[3], xi[3]);
    r1.x = fmaf(g, ys[4] - xi[4], xi[4]);
    r1.y = fmaf(g, ys[5] - xi[5], xi[5]);
    r1.z = fmaf(g, ys[6] - xi[6], xi[6]);
    r1.w = fmaf(g, ys[7] - xi[7], xi[7]);
    float4* dst = (float4*)(out + ((size_t)row * 4 + o) * DD) + l * 2;
    dst[0] = r0;
    dst[1] = r1;
  }
}

extern "C" void kernel_launch(void* const* d_in, const int* in_sizes, int n_in,
                              void* d_out, int out_size, void* d_ws, size_t ws_size,
                              hipStream_t stream) {
  const float* X = (const float*)d_in[0];
  const float* gaps = (const float*)d_in[1];
  const int* nnc = (const int*)d_in[2];
  float* out = (float*)d_out;

  float* sqv = (float*)d_ws;                                  // 32 KB
  uint4* Xb4 = (uint4*)((char*)d_ws + 32768);                 // 8 MB bf16 X
  uint* ckey = (uint*)((char*)d_ws + 32768 + 8388608);        // 4 MB candidates

  cvtsq_kernel<<<TT / 4, 256, 0, stream>>>(X, Xb4, sqv);
  gemm_topk<<<1024, 256, 0, stream>>>((const ushort*)Xb4, sqv, ckey);
  refine_gen<<<TT, 64, 0, stream>>>(X, ckey, gaps, nnc, out);
}

// Round 4
// 230.986 us; speedup vs baseline: 4.6300x; 1.1142x over previous
//
#include <hip/hip_runtime.h>

#define TT 8192
#define DD 512
#define NN 4
#define JS 16
#define JR (TT / JS)        // 512 columns per slice
#define BIGU 0xFFFFFFFFu
#define BIGF 3.0e38f

typedef unsigned int uint;
typedef unsigned short ushort;
typedef __attribute__((ext_vector_type(8))) short short8;   // 8 bf16 = 4 VGPRs
typedef __attribute__((ext_vector_type(4))) float f32x4;

// ---- fp32 -> bf16 (RTN-even) ----
__device__ __forceinline__ uint bfr(float f) {
  uint u = __float_as_uint(f);
  return (u + 0x7FFFu + ((u >> 16) & 1u)) >> 16;
}

// inverse of the orderable-uint transform (works for both sign branches)
__device__ __forceinline__ float uinv(uint x) {
  return __uint_as_float(x ^ ((uint)((int)(~x) >> 31) | 0x80000000u));
}

// fused: bf16 convert + row sum-of-squares
__global__ void cvtsq_kernel(const float* __restrict__ X, uint4* __restrict__ Xb,
                             float* __restrict__ sq) {
  int w = threadIdx.x >> 6, l = threadIdx.x & 63;
  int row = blockIdx.x * 4 + w;
  const float4* xr = (const float4*)(X + (size_t)row * DD) + l * 2;
  float4 a = xr[0], b = xr[1];
  uint4 o;
  o.x = bfr(a.x) | (bfr(a.y) << 16);
  o.y = bfr(a.z) | (bfr(a.w) << 16);
  o.z = bfr(b.x) | (bfr(b.y) << 16);
  o.w = bfr(b.z) | (bfr(b.w) << 16);
  Xb[(size_t)row * 64 + l] = o;
  float s = a.x * a.x + a.y * a.y + a.z * a.z + a.w * a.w +
            b.x * b.x + b.y * b.y + b.z * b.z + b.w * b.w;
#pragma unroll
  for (int off = 32; off >= 1; off >>= 1) s += __shfl_down(s, off, 64);
  if (l == 0) sq[row] = s;
}

// global->LDS async 16B
__device__ __forceinline__ void gload16(const void* g, void* l) {
  __builtin_amdgcn_global_load_lds(
      (const __attribute__((address_space(1))) void*)(size_t)g,
      (__attribute__((address_space(3))) void*)(uint)(size_t)l, 16, 0, 0);
}

// bf16-MFMA distance GEMM (transposed: m=j, n=i), 64x128 tile, BK=64,
// XOR-swizzled LDS, prefiltered in-register per-row top-4/lane selection
__global__ __launch_bounds__(256, 5) void gemm_topk(
    const ushort* __restrict__ Xb, const float* __restrict__ sqv,
    uint* __restrict__ ckey) {
  __shared__ char smem[24576];        // As 8K (64 rows) + Bs 16K (128 rows); merge overlays
  char* AsB = smem;                   // i-rows [64][8 x 16B chunks, slot = c^(r&7)]
  char* BsB = smem + 8192;            // j-rows [128][...], same swizzle

  const int t = threadIdx.x;
  const int w = t >> 6, l = t & 63;
  const int l15 = l & 15, q4 = l >> 4;
  const int bi = blockIdx.x >> 4;     // 128 row-blocks of 64 i-rows
  const int bs = blockIdx.x & 15;     // 16 j-slices
  const int i0 = bi * 64;
  const int js0 = bs * JR;
  const char* XbB = (const char*)Xb;
  const int mq = w * 32;              // wave's 32-wide j-quadrant

  uint L[4][4];                       // per-(lane, i-frag) top-4 packed keys
  float thrf[4];
#pragma unroll
  for (int cb = 0; cb < 4; ++cb) {
    thrf[cb] = BIGF;
#pragma unroll
    for (int s = 0; s < 4; ++s) L[cb][s] = BIGU;
  }

  for (int jt = 0; jt < JR / 128; ++jt) {
    const int jb = js0 + jt * 128;
    f32x4 acc[2][4];
#pragma unroll
    for (int rb = 0; rb < 2; ++rb)
#pragma unroll
      for (int cb = 0; cb < 4; ++cb) {
        f32x4 z = {0.f, 0.f, 0.f, 0.f};
        acc[rb][cb] = z;
      }

    for (int kt = 0; kt < DD / 64; ++kt) {     // 8 stages per j-tile
      __syncthreads();                 // readers of previous k-tile done
#pragma unroll
      for (int q = 0; q < 6; ++q) {    // 1536 chunks: 64 A-rows + 128 B-rows
        int cidx = q * 256 + t;
        int r = cidx >> 3, s = cidx & 7;
        int rowg = (r < 64) ? (i0 + r) : (jb + r - 64);
        gload16(XbB + (size_t)rowg * 1024 + kt * 128 + ((s ^ (r & 7)) << 4),
                smem + cidx * 16);
      }
      __syncthreads();
#pragma unroll
      for (int kk = 0; kk < 2; ++kk) { // two 16x16x32 k-steps per stage
        const int cc = kk * 4 + q4;
        short8 af[2], bf[4];
#pragma unroll
        for (int rb = 0; rb < 2; ++rb) {   // A-operand = j-rows (from Bs)
          int rr = mq + rb * 16 + l15;
          af[rb] = *(const short8*)(BsB + rr * 128 + ((cc ^ (rr & 7)) * 16));
        }
#pragma unroll
        for (int cb = 0; cb < 4; ++cb) {   // B-operand = i-rows (from As)
          int rr = cb * 16 + l15;
          bf[cb] = *(const short8*)(AsB + rr * 128 + ((cc ^ (rr & 7)) * 16));
        }
#pragma unroll
        for (int rb = 0; rb < 2; ++rb)
#pragma unroll
          for (int cb = 0; cb < 4; ++cb)
            acc[rb][cb] = __builtin_amdgcn_mfma_f32_16x16x32_bf16(
                af[rb], bf[cb], acc[rb][cb], 0, 0, 0);
      }
    }

    // selection: key = sq[j] - 2*dot (sq[i] const per row -> order-equivalent)
    // D layout: col(lane&15)=i-local, row(q4*4+reg)=j-local
#pragma unroll
    for (int rb = 0; rb < 2; ++rb) {
      int jg = jb + mq + rb * 16 + q4 * 4;
      float4 sj = *(const float4*)(sqv + jg);
      float s4[4] = {sj.x, sj.y, sj.z, sj.w};
#pragma unroll
      for (int cb = 0; cb < 4; ++cb) {
        float kf[4];
#pragma unroll
        for (int r = 0; r < 4; ++r) kf[r] = fmaf(-2.f, acc[rb][cb][r], s4[r]);
        float mn = fminf(fminf(kf[0], kf[1]), fminf(kf[2], kf[3]));
        if (mn <= thrf[cb]) {          // rare slow path
#pragma unroll
          for (int r = 0; r < 4; ++r) {
            uint u = __float_as_uint(kf[r]);
            u ^= (uint)((int)u >> 31) | 0x80000000u;       // orderable uint
            uint p = (u & 0xFFFFE000u) | (uint)(jg + r);   // 19b key | 13b j
            if (p < L[cb][3]) {
              L[cb][3] = p;
#pragma unroll
              for (int s = 3; s >= 1; --s) {
                uint lo = L[cb][s - 1], hi = L[cb][s];
                bool sw = hi < lo;
                L[cb][s - 1] = sw ? hi : lo;
                L[cb][s] = sw ? lo : hi;
              }
            }
          }
          uint l3 = L[cb][3];
          thrf[cb] = (l3 == BIGU) ? BIGF : uinv(l3 | 0x1FFFu);
        }
      }
    }
  }

  __syncthreads();                     // done with As/Bs; overlay merge buffer
  uint* ml = (uint*)smem;              // [64 rows][65]
  const int cid = w * 4 + q4;          // 16 contributors per row
#pragma unroll
  for (int cb = 0; cb < 4; ++cb) {
    int n = cb * 16 + l15;
#pragma unroll
    for (int s = 0; s < 4; ++s) ml[n * 65 + cid * 4 + s] = L[cb][s];
  }
  __syncthreads();
  if (t < 64) {
    uint best[8];
#pragma unroll
    for (int s = 0; s < 8; ++s) best[s] = BIGU;
    for (int u = 0; u < 64; ++u) {
      uint p = ml[t * 65 + u];
      if (p < best[7]) {
        best[7] = p;
#pragma unroll
        for (int s = 7; s >= 1; --s) {
          uint lo = best[s - 1], hi = best[s];
          bool sw = hi < lo;
          best[s - 1] = sw ? hi : lo;
          best[s] = sw ? lo : hi;
        }
      }
    }
#pragma unroll
    for (int s = 0; s < 8; ++s)
      ckey[(size_t)(i0 + t) * 128 + bs * 8 + s] = best[s];
  }
}

// fused: approx-top-8 of 128 candidates, exact fp64 re-rank, interpolate + write
// 4 rows per 256-thread block (one wave per row)
__global__ __launch_bounds__(256) void refine_gen(
    const float* __restrict__ X, const uint* __restrict__ ckey,
    const float* __restrict__ gaps, const int* __restrict__ nnc,
    float* __restrict__ out) {
  const int row = blockIdx.x * 4 + (threadIdx.x >> 6);
  const int l = threadIdx.x & 63;
  uint k0 = ckey[(size_t)row * 128 + l];
  uint k1 = ckey[(size_t)row * 128 + 64 + l];

  float xi[8];
  const float4* xr = (const float4*)(X + (size_t)row * DD) + l * 2;
  float4 xa = xr[0], xb = xr[1];
  xi[0] = xa.x; xi[1] = xa.y; xi[2] = xa.z; xi[3] = xa.w;
  xi[4] = xb.x; xi[5] = xb.y; xi[6] = xb.z; xi[7] = xb.w;

  int selj[8];
#pragma unroll
  for (int s = 0; s < 8; ++s) {
    uint m = k0 < k1 ? k0 : k1;
#pragma unroll
    for (int off = 32; off >= 1; off >>= 1) {
      uint o = __shfl_down(m, off, 64);
      m = o < m ? o : m;
    }
    m = __shfl(m, 0, 64);
    selj[s] = (int)(m & 8191u);        // j embedded; packed values unique
    if (k0 == m) k0 = BIGU;
    if (k1 == m) k1 = BIGU;
  }

  float yv[8][8];
  double ex[8];
#pragma unroll
  for (int s = 0; s < 8; ++s) {
    const float4* yr = (const float4*)(X + (size_t)selj[s] * DD) + l * 2;
    float4 ya = yr[0], yb = yr[1];
    yv[s][0] = ya.x; yv[s][1] = ya.y; yv[s][2] = ya.z; yv[s][3] = ya.w;
    yv[s][4] = yb.x; yv[s][5] = yb.y; yv[s][6] = yb.z; yv[s][7] = yb.w;
    double a = 0.0;
#pragma unroll
    for (int m = 0; m < 8; ++m) {
      double df = (double)xi[m] - (double)yv[s][m];
      a += df * df;
    }
#pragma unroll
    for (int off = 32; off >= 1; off >>= 1) a += __shfl_down(a, off, 64);
    ex[s] = __shfl(a, 0, 64);          // broadcast to all lanes
  }

  int rk[8];                           // exact ranks (rank 0 = self)
#pragma unroll
  for (int s = 0; s < 8; ++s) {
    int r = 0;
#pragma unroll
    for (int u = 0; u < 8; ++u)
      if (ex[u] < ex[s] || (ex[u] == ex[s] && selj[u] < selj[s])) ++r;
    rk[s] = r;
  }

#pragma unroll
  for (int o = 0; o < 4; ++o) {
    float g = gaps[row * 4 + o];
    int target = nnc[row * 4 + o] + 1; // skip self (rank 0)
    float ys[8];
#pragma unroll
    for (int m = 0; m < 8; ++m) ys[m] = 0.f;
#pragma unroll
    for (int s = 0; s < 8; ++s) {
      bool hit = (rk[s] == target);
#pragma unroll
      for (int m = 0; m < 8; ++m) ys[m] = hit ? yv[s][m] : ys[m];
    }
    float4 r0, r1;
    r0.x = fmaf(g, ys[0] - xi[0], xi[0]);
    r0.y = fmaf(g, ys[1] - xi[1], xi[1]);
    r0.z = fmaf(g, ys[2] - xi[2], xi[2]);
    r0.w = fmaf(g, ys[3] - xi[3], xi[3]);
    r1.x = fmaf(g, ys[4] - xi[4], xi[4]);
    r1.y = fmaf(g, ys[5] - xi[5], xi[5]);
    r1.z = fmaf(g, ys[6] - xi[6], xi[6]);
    r1.w = fmaf(g, ys[7] - xi[7], xi[7]);
    float4* dst = (float4*)(out + ((size_t)row * 4 + o) * DD) + l * 2;
    dst[0] = r0;
    dst[1] = r1;
  }
}

extern "C" void kernel_launch(void* const* d_in, const int* in_sizes, int n_in,
                              void* d_out, int out_size, void* d_ws, size_t ws_size,
                              hipStream_t stream) {
  const float* X = (const float*)d_in[0];
  const float* gaps = (const float*)d_in[1];
  const int* nnc = (const int*)d_in[2];
  float* out = (float*)d_out;

  float* sqv = (float*)d_ws;                                  // 32 KB
  uint4* Xb4 = (uint4*)((char*)d_ws + 32768);                 // 8 MB bf16 X
  uint* ckey = (uint*)((char*)d_ws + 32768 + 8388608);        // 4 MB candidates

  cvtsq_kernel<<<TT / 4, 256, 0, stream>>>(X, Xb4, sqv);
  gemm_topk<<<2048, 256, 0, stream>>>((const ushort*)Xb4, sqv, ckey);
  refine_gen<<<TT / 4, 256, 0, stream>>>(X, ckey, gaps, nnc, out);
}

// Round 5
// 225.199 us; speedup vs baseline: 4.7490x; 1.0257x over previous
//
#include <hip/hip_runtime.h>

#define TT 8192
#define DD 512
#define NN 4
#define JS 16
#define JR (TT / JS)        // 512 columns per slice
#define BIGU 0xFFFFFFFFu
#define BIGF 3.0e38f

typedef unsigned int uint;
typedef unsigned short ushort;
typedef __attribute__((ext_vector_type(8))) short short8;   // 8 bf16 = 4 VGPRs
typedef __attribute__((ext_vector_type(4))) float f32x4;

// ---- fp32 -> bf16 (RTN-even) ----
__device__ __forceinline__ uint bfr(float f) {
  uint u = __float_as_uint(f);
  return (u + 0x7FFFu + ((u >> 16) & 1u)) >> 16;
}

// inverse of the orderable-uint transform (works for both sign branches)
__device__ __forceinline__ float uinv(uint x) {
  return __uint_as_float(x ^ ((uint)((int)(~x) >> 31) | 0x80000000u));
}

// fused: bf16 convert + row sum-of-squares
__global__ void cvtsq_kernel(const float* __restrict__ X, uint4* __restrict__ Xb,
                             float* __restrict__ sq) {
  int w = threadIdx.x >> 6, l = threadIdx.x & 63;
  int row = blockIdx.x * 4 + w;
  const float4* xr = (const float4*)(X + (size_t)row * DD) + l * 2;
  float4 a = xr[0], b = xr[1];
  uint4 o;
  o.x = bfr(a.x) | (bfr(a.y) << 16);
  o.y = bfr(a.z) | (bfr(a.w) << 16);
  o.z = bfr(b.x) | (bfr(b.y) << 16);
  o.w = bfr(b.z) | (bfr(b.w) << 16);
  Xb[(size_t)row * 64 + l] = o;
  float s = a.x * a.x + a.y * a.y + a.z * a.z + a.w * a.w +
            b.x * b.x + b.y * b.y + b.z * b.z + b.w * b.w;
#pragma unroll
  for (int off = 32; off >= 1; off >>= 1) s += __shfl_down(s, off, 64);
  if (l == 0) sq[row] = s;
}

// global->LDS async 16B
__device__ __forceinline__ void gload16(const void* g, void* l) {
  __builtin_amdgcn_global_load_lds(
      (const __attribute__((address_space(1))) void*)(size_t)g,
      (__attribute__((address_space(3))) void*)(uint)(size_t)l, 16, 0, 0);
}

// bf16-MFMA distance GEMM (transposed: m=j, n=i), 64x128 tile, BK=64,
// double-buffered LDS (1 barrier/stage, cross-stage DMA prefetch),
// XOR-swizzled layout, prefiltered in-register per-row top-4/lane selection
__global__ __launch_bounds__(256, 3) void gemm_topk(
    const ushort* __restrict__ Xb, const float* __restrict__ sqv,
    uint* __restrict__ ckey) {
  __shared__ char smem[49152];        // 2 x 24 KB stage buffers; merge overlays buf0

  const int t = threadIdx.x;
  const int w = t >> 6, l = t & 63;
  const int l15 = l & 15, q4 = l >> 4;
  const int bi = blockIdx.x >> 4;     // 128 row-blocks of 64 i-rows
  const int bs = blockIdx.x & 15;     // 16 j-slices
  const int i0 = bi * 64;
  const int js0 = bs * JR;
  const char* XbB = (const char*)Xb;
  const int mq = w * 32;              // wave's 32-wide j-quadrant

  // loop-invariant staging addresses: 6 chunks/thread per stage
  const char* gQ[6]; uint dstQ[6]; bool isB[6];
#pragma unroll
  for (int q = 0; q < 6; ++q) {
    int cidx = q * 256 + t;
    int r = cidx >> 3;
    int sc = (cidx & 7) ^ (r & 7);    // swizzled source chunk slot
    isB[q] = (r >= 64);
    int rowl = isB[q] ? (r - 64) : (i0 + r);
    gQ[q] = XbB + (size_t)rowl * 1024 + sc * 16;
    dstQ[q] = (uint)cidx * 16;
  }

  uint L[4][4];                       // per-(lane, i-frag) top-4 packed keys
  float thrf[4];
#pragma unroll
  for (int cb = 0; cb < 4; ++cb) {
    thrf[cb] = BIGF;
#pragma unroll
    for (int s = 0; s < 4; ++s) L[cb][s] = BIGU;
  }

  f32x4 acc[2][4];
#pragma unroll
  for (int rb = 0; rb < 2; ++rb)
#pragma unroll
    for (int cb = 0; cb < 4; ++cb) {
      f32x4 z = {0.f, 0.f, 0.f, 0.f};
      acc[rb][cb] = z;
    }

  {  // prologue: DMA stage 0 into buf0
    size_t jb0 = (size_t)js0 * 1024;
#pragma unroll
    for (int q = 0; q < 6; ++q)
      gload16(gQ[q] + (isB[q] ? jb0 : 0), smem + dstQ[q]);
  }

  for (int s = 0; s < 32; ++s) {      // 4 j-tiles x 8 k-stages, linearized
    const int kt = s & 7, jt = s >> 3;
    __syncthreads();                  // drains stage-s DMA; fences buf^1 readers

    {  // prefetch stage s+1 into the other buffer (wraps harmlessly at s=31)
      const int sn = (s + 1) & 31;
      const size_t jbn = (size_t)(js0 + (sn >> 3) * 128) * 1024;
      const size_t ko = (size_t)((sn & 7) * 128);
      char* dbase = smem + ((s + 1) & 1) * 24576;
#pragma unroll
      for (int q = 0; q < 6; ++q)
        gload16(gQ[q] + (isB[q] ? jbn : 0) + ko, dbase + dstQ[q]);
    }

    {  // compute stage s from current buffer
      const char* AsB = smem + (s & 1) * 24576;   // i-rows [64][8x16B swizzled]
      const char* BsB = AsB + 8192;               // j-rows [128][...]
#pragma unroll
      for (int kk = 0; kk < 2; ++kk) {
        const int cc = kk * 4 + q4;
        short8 af[2], bf[4];
#pragma unroll
        for (int rb = 0; rb < 2; ++rb) {   // A-operand = j-rows
          int rr = mq + rb * 16 + l15;
          af[rb] = *(const short8*)(BsB + rr * 128 + ((cc ^ (rr & 7)) * 16));
        }
#pragma unroll
        for (int cb = 0; cb < 4; ++cb) {   // B-operand = i-rows
          int rr = cb * 16 + l15;
          bf[cb] = *(const short8*)(AsB + rr * 128 + ((cc ^ (rr & 7)) * 16));
        }
#pragma unroll
        for (int rb = 0; rb < 2; ++rb)
#pragma unroll
          for (int cb = 0; cb < 4; ++cb)
            acc[rb][cb] = __builtin_amdgcn_mfma_f32_16x16x32_bf16(
                af[rb], bf[cb], acc[rb][cb], 0, 0, 0);
      }
    }

    if (kt == 7) {                    // per-j-tile selection epilogue
      const int jb = js0 + jt * 128;
      // key = sq[j] - 2*dot; D layout: col(lane&15)=i-local, row(q4*4+reg)=j-local
#pragma unroll
      for (int rb = 0; rb < 2; ++rb) {
        int jg = jb + mq + rb * 16 + q4 * 4;
        float4 sj = *(const float4*)(sqv + jg);
        float s4[4] = {sj.x, sj.y, sj.z, sj.w};
#pragma unroll
        for (int cb = 0; cb < 4; ++cb) {
          float kf[4];
#pragma unroll
          for (int r = 0; r < 4; ++r) kf[r] = fmaf(-2.f, acc[rb][cb][r], s4[r]);
          float mn = fminf(fminf(kf[0], kf[1]), fminf(kf[2], kf[3]));
          if (mn <= thrf[cb]) {       // rare slow path
#pragma unroll
            for (int r = 0; r < 4; ++r) {
              uint u = __float_as_uint(kf[r]);
              u ^= (uint)((int)u >> 31) | 0x80000000u;       // orderable uint
              uint p = (u & 0xFFFFE000u) | (uint)(jg + r);   // 19b key | 13b j
              if (p < L[cb][3]) {
                L[cb][3] = p;
#pragma unroll
                for (int x = 3; x >= 1; --x) {
                  uint lo = L[cb][x - 1], hi = L[cb][x];
                  bool sw = hi < lo;
                  L[cb][x - 1] = sw ? hi : lo;
                  L[cb][x] = sw ? lo : hi;
                }
              }
            }
            uint l3 = L[cb][3];
            thrf[cb] = (l3 == BIGU) ? BIGF : uinv(l3 | 0x1FFFu);
          }
        }
      }
      // re-zero accumulators for next j-tile
#pragma unroll
      for (int rb = 0; rb < 2; ++rb)
#pragma unroll
        for (int cb = 0; cb < 4; ++cb) {
          f32x4 z = {0.f, 0.f, 0.f, 0.f};
          acc[rb][cb] = z;
        }
    }
  }

  __syncthreads();                     // done with stage buffers; overlay merge
  uint* ml = (uint*)smem;              // [64 rows][65]
  const int cid = w * 4 + q4;          // 16 contributors per row
#pragma unroll
  for (int cb = 0; cb < 4; ++cb) {
    int n = cb * 16 + l15;
#pragma unroll
    for (int s = 0; s < 4; ++s) ml[n * 65 + cid * 4 + s] = L[cb][s];
  }
  __syncthreads();
  if (t < 64) {
    uint best[8];
#pragma unroll
    for (int s = 0; s < 8; ++s) best[s] = BIGU;
    for (int u = 0; u < 64; ++u) {
      uint p = ml[t * 65 + u];
      if (p < best[7]) {
        best[7] = p;
#pragma unroll
        for (int s = 7; s >= 1; --s) {
          uint lo = best[s - 1], hi = best[s];
          bool sw = hi < lo;
          best[s - 1] = sw ? hi : lo;
          best[s] = sw ? lo : hi;
        }
      }
    }
#pragma unroll
    for (int s = 0; s < 8; ++s)
      ckey[(size_t)(i0 + t) * 128 + bs * 8 + s] = best[s];
  }
}

// fused: approx-top-8 of 128 candidates, exact fp64 re-rank, interpolate + write
// 4 rows per 256-thread block (one wave per row)
__global__ __launch_bounds__(256) void refine_gen(
    const float* __restrict__ X, const uint* __restrict__ ckey,
    const float* __restrict__ gaps, const int* __restrict__ nnc,
    float* __restrict__ out) {
  const int row = blockIdx.x * 4 + (threadIdx.x >> 6);
  const int l = threadIdx.x & 63;
  uint k0 = ckey[(size_t)row * 128 + l];
  uint k1 = ckey[(size_t)row * 128 + 64 + l];

  float xi[8];
  const float4* xr = (const float4*)(X + (size_t)row * DD) + l * 2;
  float4 xa = xr[0], xb = xr[1];
  xi[0] = xa.x; xi[1] = xa.y; xi[2] = xa.z; xi[3] = xa.w;
  xi[4] = xb.x; xi[5] = xb.y; xi[6] = xb.z; xi[7] = xb.w;

  int selj[8];
#pragma unroll
  for (int s = 0; s < 8; ++s) {
    uint m = k0 < k1 ? k0 : k1;
#pragma unroll
    for (int off = 32; off >= 1; off >>= 1) {
      uint o = __shfl_down(m, off, 64);
      m = o < m ? o : m;
    }
    m = __shfl(m, 0, 64);
    selj[s] = (int)(m & 8191u);        // j embedded; packed values unique
    if (k0 == m) k0 = BIGU;
    if (k1 == m) k1 = BIGU;
  }

  float yv[8][8];
  double ex[8];
#pragma unroll
  for (int s = 0; s < 8; ++s) {
    const float4* yr = (const float4*)(X + (size_t)selj[s] * DD) + l * 2;
    float4 ya = yr[0], yb = yr[1];
    yv[s][0] = ya.x; yv[s][1] = ya.y; yv[s][2] = ya.z; yv[s][3] = ya.w;
    yv[s][4] = yb.x; yv[s][5] = yb.y; yv[s][6] = yb.z; yv[s][7] = yb.w;
    double a = 0.0;
#pragma unroll
    for (int m = 0; m < 8; ++m) {
      double df = (double)xi[m] - (double)yv[s][m];
      a += df * df;
    }
#pragma unroll
    for (int off = 32; off >= 1; off >>= 1) a += __shfl_down(a, off, 64);
    ex[s] = __shfl(a, 0, 64);          // broadcast to all lanes
  }

  int rk[8];                           // exact ranks (rank 0 = self)
#pragma unroll
  for (int s = 0; s < 8; ++s) {
    int r = 0;
#pragma unroll
    for (int u = 0; u < 8; ++u)
      if (ex[u] < ex[s] || (ex[u] == ex[s] && selj[u] < selj[s])) ++r;
    rk[s] = r;
  }

#pragma unroll
  for (int o = 0; o < 4; ++o) {
    float g = gaps[row * 4 + o];
    int target = nnc[row * 4 + o] + 1; // skip self (rank 0)
    float ys[8];
#pragma unroll
    for (int m = 0; m < 8; ++m) ys[m] = 0.f;
#pragma unroll
    for (int s = 0; s < 8; ++s) {
      bool hit = (rk[s] == target);
#pragma unroll
      for (int m = 0; m < 8; ++m) ys[m] = hit ? yv[s][m] : ys[m];
    }
    float4 r0, r1;
    r0.x = fmaf(g, ys[0] - xi[0], xi[0]);
    r0.y = fmaf(g, ys[1] - xi[1], xi[1]);
    r0.z = fmaf(g, ys[2] - xi[2], xi[2]);
    r0.w = fmaf(g, ys[3] - xi[3], xi[3]);
    r1.x = fmaf(g, ys[4] - xi[4], xi[4]);
    r1.y = fmaf(g, ys[5] - xi[5], xi[5]);
    r1.z = fmaf(g, ys[6] - xi[6], xi[6]);
    r1.w = fmaf(g, ys[7] - xi[7], xi[7]);
    float4* dst = (float4*)(out + ((size_t)row * 4 + o) * DD) + l * 2;
    dst[0] = r0;
    dst[1] = r1;
  }
}

extern "C" void kernel_launch(void* const* d_in, const int* in_sizes, int n_in,
                              void* d_out, int out_size, void* d_ws, size_t ws_size,
                              hipStream_t stream) {
  const float* X = (const float*)d_in[0];
  const float* gaps = (const float*)d_in[1];
  const int* nnc = (const int*)d_in[2];
  float* out = (float*)d_out;

  float* sqv = (float*)d_ws;                                  // 32 KB
  uint4* Xb4 = (uint4*)((char*)d_ws + 32768);                 // 8 MB bf16 X
  uint* ckey = (uint*)((char*)d_ws + 32768 + 8388608);        // 4 MB candidates

  cvtsq_kernel<<<TT / 4, 256, 0, stream>>>(X, Xb4, sqv);
  gemm_topk<<<2048, 256, 0, stream>>>((const ushort*)Xb4, sqv, ckey);
  refine_gen<<<TT / 4, 256, 0, stream>>>(X, ckey, gaps, nnc, out);
}

// Round 6
// 212.167 us; speedup vs baseline: 5.0407x; 1.0614x over previous
//
#include <hip/hip_runtime.h>

#define TT 8192
#define DD 512
#define NN 4
#define JS 16
#define JR (TT / JS)        // 512 columns per slice
#define BIGU 0xFFFFFFFFu

typedef unsigned int uint;
typedef unsigned short ushort;
typedef __attribute__((ext_vector_type(8))) short short8;   // 8 bf16 = 4 VGPRs
typedef __attribute__((ext_vector_type(4))) float f32x4;

// ---- fp32 -> bf16 (RTN-even) ----
__device__ __forceinline__ uint bfr(float f) {
  uint u = __float_as_uint(f);
  return (u + 0x7FFFu + ((u >> 16) & 1u)) >> 16;
}

// fused: bf16 convert + row sum-of-squares
__global__ void cvtsq_kernel(const float* __restrict__ X, uint4* __restrict__ Xb,
                             float* __restrict__ sq) {
  int w = threadIdx.x >> 6, l = threadIdx.x & 63;
  int row = blockIdx.x * 4 + w;
  const float4* xr = (const float4*)(X + (size_t)row * DD) + l * 2;
  float4 a = xr[0], b = xr[1];
  uint4 o;
  o.x = bfr(a.x) | (bfr(a.y) << 16);
  o.y = bfr(a.z) | (bfr(a.w) << 16);
  o.z = bfr(b.x) | (bfr(b.y) << 16);
  o.w = bfr(b.z) | (bfr(b.w) << 16);
  Xb[(size_t)row * 64 + l] = o;
  float s = a.x * a.x + a.y * a.y + a.z * a.z + a.w * a.w +
            b.x * b.x + b.y * b.y + b.z * b.z + b.w * b.w;
#pragma unroll
  for (int off = 32; off >= 1; off >>= 1) s += __shfl_down(s, off, 64);
  if (l == 0) sq[row] = s;
}

// global->LDS async 16B
__device__ __forceinline__ void gload16(const void* g, void* l) {
  __builtin_amdgcn_global_load_lds(
      (const __attribute__((address_space(1))) void*)(size_t)g,
      (__attribute__((address_space(3))) void*)(uint)(size_t)l, 16, 0, 0);
}

// 3-term XOR swizzle: row r (64B = 4x16B chunks), slot s holds source chunk s^g(r).
// Guarantees every 16-lane b128 read phase covers each 4-bank group exactly 2x.
__device__ __forceinline__ int swz(int r) {
  return (r & 3) ^ ((r >> 1) & 2) ^ ((r >> 3) & 1);
}

// bf16-MFMA distance GEMM (transposed: m=j, n=i), 128x128 tile, BK=32,
// double-buffered LDS (2x16KB, 1 barrier/stage, cross-stage DMA prefetch),
// in-register per-row top-4/lane streaming selection
__global__ __launch_bounds__(256, 4) void gemm_topk(
    const ushort* __restrict__ Xb, const float* __restrict__ sqv,
    uint* __restrict__ ckey) {
  __shared__ char smem[32768];        // 2 stage buffers; merge overlays

  const int t = threadIdx.x;
  const int w = t >> 6, l = t & 63;
  const int l15 = l & 15, q4 = l >> 4;
  const int bi = blockIdx.x >> 4;     // 64 row-blocks of 128 i-rows
  const int bs = blockIdx.x & 15;     // 16 j-slices
  const int i0 = bi * 128;
  const int js0 = bs * JR;
  const char* XbB = (const char*)Xb;
  const int mq = (w & 1) * 64;        // wave's j-quadrant
  const int nq = (w >> 1) * 64;       // wave's i-quadrant

  // loop-invariant staging addresses: 4 chunks/thread per stage
  // cells 0..511 = 128 i-rows x 4 slots; cells 512..1023 = 128 j-rows x 4 slots
  const char* gQ[4];
#pragma unroll
  for (int q = 0; q < 4; ++q) {
    int cidx = q * 256 + t;
    int r = cidx >> 2, slot = cidx & 3;
    int cs = slot ^ swz(r);
    int rowg = (r < 128) ? (i0 + r) : (js0 + r - 128);
    gQ[q] = XbB + (size_t)rowg * 1024 + cs * 16;
  }

  uint L[4][4];                       // per-(lane, i-frag) top-4 packed keys
#pragma unroll
  for (int cb = 0; cb < 4; ++cb)
#pragma unroll
    for (int s = 0; s < 4; ++s) L[cb][s] = BIGU;

  f32x4 acc[4][4];
#pragma unroll
  for (int rb = 0; rb < 4; ++rb)
#pragma unroll
    for (int cb = 0; cb < 4; ++cb) {
      f32x4 z = {0.f, 0.f, 0.f, 0.f};
      acc[rb][cb] = z;
    }

  {  // prologue: DMA stage 0 into buf0
#pragma unroll
    for (int q = 0; q < 4; ++q)
      gload16(gQ[q], smem + (q * 256 + t) * 16);
  }

  // per-lane LDS read cells (loop-invariant except buffer base)
  int cellA[4], cellB[4];
#pragma unroll
  for (int rb = 0; rb < 4; ++rb) {
    int rj = 128 + mq + rb * 16 + l15;
    cellA[rb] = rj * 4 + (q4 ^ swz(rj));
  }
#pragma unroll
  for (int cb = 0; cb < 4; ++cb) {
    int ri = nq + cb * 16 + l15;
    cellB[cb] = ri * 4 + (q4 ^ swz(ri));
  }

  for (int s = 0; s < 64; ++s) {      // 4 j-tiles x 16 k-stages, linearized
    const int kt = s & 15, jt = s >> 4;
    __syncthreads();                  // drains stage-s DMA; fences buf^1 readers

    {  // prefetch stage s+1 into the other buffer (wraps harmlessly at s=63)
      const int sn = (s + 1) & 63;
      const int ioff = (sn & 15) * 64;
      const int joff = ioff + (sn >> 4) * 131072;
      char* dbase = smem + ((s + 1) & 1) * 16384;
#pragma unroll
      for (int q = 0; q < 4; ++q)
        gload16(gQ[q] + (q < 2 ? ioff : joff), dbase + (q * 256 + t) * 16);
    }

    {  // compute stage s from current buffer (one 16x16x32 k-step)
      const char* base = smem + (s & 1) * 16384;
      short8 af[4], bf[4];
#pragma unroll
      for (int rb = 0; rb < 4; ++rb)
        af[rb] = *(const short8*)(base + cellA[rb] * 16);
#pragma unroll
      for (int cb = 0; cb < 4; ++cb)
        bf[cb] = *(const short8*)(base + cellB[cb] * 16);
#pragma unroll
      for (int rb = 0; rb < 4; ++rb)
#pragma unroll
        for (int cb = 0; cb < 4; ++cb)
          acc[rb][cb] = __builtin_amdgcn_mfma_f32_16x16x32_bf16(
              af[rb], bf[cb], acc[rb][cb], 0, 0, 0);
    }

    if (kt == 15) {                   // per-j-tile selection epilogue
      const int jb = js0 + jt * 128;
      // key = sq[j] - 2*dot; D layout: col(lane&15)=i-local, row(q4*4+reg)=j-local
#pragma unroll
      for (int rb = 0; rb < 4; ++rb) {
        int jg = jb + mq + rb * 16 + q4 * 4;
        float4 sj = *(const float4*)(sqv + jg);
        float s4[4] = {sj.x, sj.y, sj.z, sj.w};
#pragma unroll
        for (int cb = 0; cb < 4; ++cb) {
#pragma unroll
          for (int r = 0; r < 4; ++r) {
            float key = fmaf(-2.f, acc[rb][cb][r], s4[r]);
            uint u = __float_as_uint(key);
            u ^= (uint)((int)u >> 31) | 0x80000000u;       // orderable uint
            uint p = (u & 0xFFFFE000u) | (uint)(jg + r);   // 19b key | 13b j
            if (p < L[cb][3]) {
              L[cb][3] = p;
#pragma unroll
              for (int x = 3; x >= 1; --x) {
                uint lo = L[cb][x - 1], hi = L[cb][x];
                bool sw = hi < lo;
                L[cb][x - 1] = sw ? hi : lo;
                L[cb][x] = sw ? lo : hi;
              }
            }
          }
        }
      }
      // re-zero accumulators for next j-tile
#pragma unroll
      for (int rb = 0; rb < 4; ++rb)
#pragma unroll
        for (int cb = 0; cb < 4; ++cb) {
          f32x4 z = {0.f, 0.f, 0.f, 0.f};
          acc[rb][cb] = z;
        }
    }
  }

  __syncthreads();                     // drains wrap DMA; overlay merge buffer
  uint* ml = (uint*)smem;              // [128 rows][33]
  const int cid = (w & 1) * 4 + q4;    // 8 contributors per row
#pragma unroll
  for (int cb = 0; cb < 4; ++cb) {
    int n = nq + cb * 16 + l15;
#pragma unroll
    for (int s = 0; s < 4; ++s) ml[n * 33 + cid * 4 + s] = L[cb][s];
  }
  __syncthreads();
  if (t < 128) {
    uint best[8];
#pragma unroll
    for (int s = 0; s < 8; ++s) best[s] = BIGU;
    for (int u = 0; u < 32; ++u) {
      uint p = ml[t * 33 + u];
      if (p < best[7]) {
        best[7] = p;
#pragma unroll
        for (int s = 7; s >= 1; --s) {
          uint lo = best[s - 1], hi = best[s];
          bool sw = hi < lo;
          best[s - 1] = sw ? hi : lo;
          best[s] = sw ? lo : hi;
        }
      }
    }
#pragma unroll
    for (int s = 0; s < 8; ++s)
      ckey[(size_t)(i0 + t) * 128 + bs * 8 + s] = best[s];
  }
}

// fused: LDS rank-count top-8 of 128 candidates, exact fp64 re-rank,
// interpolate + write. 4 rows per 256-thread block (one wave per row).
__global__ __launch_bounds__(256) void refine_gen(
    const float* __restrict__ X, const uint* __restrict__ ckey,
    const float* __restrict__ gaps, const int* __restrict__ nnc,
    float* __restrict__ out) {
  __shared__ uint keys[4][128];
  __shared__ uint seln[4][8];
  const int w = threadIdx.x >> 6, l = threadIdx.x & 63;
  const int row = blockIdx.x * 4 + w;
  uint k0 = ckey[(size_t)row * 128 + l];
  uint k1 = ckey[(size_t)row * 128 + 64 + l];
  keys[w][l] = k0;
  keys[w][64 + l] = k1;
  __syncthreads();

  // exact rank of each key among the 128 (keys unique) — no serial shfl chain
  int r0 = 0, r1 = 0;
  const uint4* kk = (const uint4*)keys[w];
#pragma unroll
  for (int i = 0; i < 32; ++i) {
    uint4 v = kk[i];
    r0 += (v.x < k0) + (v.y < k0) + (v.z < k0) + (v.w < k0);
    r1 += (v.x < k1) + (v.y < k1) + (v.z < k1) + (v.w < k1);
  }
  if (r0 < 8) seln[w][r0] = k0 & 8191u;
  if (r1 < 8) seln[w][r1] = k1 & 8191u;
  __syncthreads();

  int selj[8];
#pragma unroll
  for (int s = 0; s < 8; ++s) selj[s] = (int)seln[w][s];  // ascending approx key

  float xi[8];
  const float4* xr = (const float4*)(X + (size_t)row * DD) + l * 2;
  float4 xa = xr[0], xb = xr[1];
  xi[0] = xa.x; xi[1] = xa.y; xi[2] = xa.z; xi[3] = xa.w;
  xi[4] = xb.x; xi[5] = xb.y; xi[6] = xb.z; xi[7] = xb.w;

  float yv[8][8];
  double ex[8];
#pragma unroll
  for (int s = 0; s < 8; ++s) {
    const float4* yr = (const float4*)(X + (size_t)selj[s] * DD) + l * 2;
    float4 ya = yr[0], yb = yr[1];
    yv[s][0] = ya.x; yv[s][1] = ya.y; yv[s][2] = ya.z; yv[s][3] = ya.w;
    yv[s][4] = yb.x; yv[s][5] = yb.y; yv[s][6] = yb.z; yv[s][7] = yb.w;
    double a = 0.0;
#pragma unroll
    for (int m = 0; m < 8; ++m) {
      double df = (double)xi[m] - (double)yv[s][m];
      a += df * df;
    }
#pragma unroll
    for (int off = 32; off >= 1; off >>= 1) a += __shfl_down(a, off, 64);
    ex[s] = __shfl(a, 0, 64);          // broadcast to all lanes
  }

  int rk[8];                           // exact ranks (rank 0 = self)
#pragma unroll
  for (int s = 0; s < 8; ++s) {
    int r = 0;
#pragma unroll
    for (int u = 0; u < 8; ++u)
      if (ex[u] < ex[s] || (ex[u] == ex[s] && selj[u] < selj[s])) ++r;
    rk[s] = r;
  }

#pragma unroll
  for (int o = 0; o < 4; ++o) {
    float g = gaps[row * 4 + o];
    int target = nnc[row * 4 + o] + 1; // skip self (rank 0)
    float ys[8];
#pragma unroll
    for (int m = 0; m < 8; ++m) ys[m] = 0.f;
#pragma unroll
    for (int s = 0; s < 8; ++s) {
      bool hit = (rk[s] == target);
#pragma unroll
      for (int m = 0; m < 8; ++m) ys[m] = hit ? yv[s][m] : ys[m];
    }
    float4 r0v, r1v;
    r0v.x = fmaf(g, ys[0] - xi[0], xi[0]);
    r0v.y = fmaf(g, ys[1] - xi[1], xi[1]);
    r0v.z = fmaf(g, ys[2] - xi[2], xi[2]);
    r0v.w = fmaf(g, ys[3] - xi[3], xi[3]);
    r1v.x = fmaf(g, ys[4] - xi[4], xi[4]);
    r1v.y = fmaf(g, ys[5] - xi[5], xi[5]);
    r1v.z = fmaf(g, ys[6] - xi[6], xi[6]);
    r1v.w = fmaf(g, ys[7] - xi[7], xi[7]);
    float4* dst = (float4*)(out + ((size_t)row * 4 + o) * DD) + l * 2;
    dst[0] = r0v;
    dst[1] = r1v;
  }
}

extern "C" void kernel_launch(void* const* d_in, const int* in_sizes, int n_in,
                              void* d_out, int out_size, void* d_ws, size_t ws_size,
                              hipStream_t stream) {
  const float* X = (const float*)d_in[0];
  const float* gaps = (const float*)d_in[1];
  const int* nnc = (const int*)d_in[2];
  float* out = (float*)d_out;

  float* sqv = (float*)d_ws;                                  // 32 KB
  uint4* Xb4 = (uint4*)((char*)d_ws + 32768);                 // 8 MB bf16 X
  uint* ckey = (uint*)((char*)d_ws + 32768 + 8388608);        // 4 MB candidates

  cvtsq_kernel<<<TT / 4, 256, 0, stream>>>(X, Xb4, sqv);
  gemm_topk<<<1024, 256, 0, stream>>>((const ushort*)Xb4, sqv, ckey);
  refine_gen<<<TT / 4, 256, 0, stream>>>(X, ckey, gaps, nnc, out);
}